// Round 10
// baseline (246.976 us; speedup 1.0000x reference)
//
#include <hip/hip_runtime.h>
#include <hip/hip_bf16.h>
#include <stdint.h>

// B=2, L=S=2048, D_MODEL=1024, H=16, E=64. Inputs/outputs fp32; intermediates bf16.
#define BATCH 2
#define SEQ   2048
#define DM    1024
#define NH    16
#define EH    64
#define MROWS (BATCH*SEQ)   // 4096

typedef __attribute__((ext_vector_type(8))) short  short8;   // MFMA A/B frag (8 bf16)
typedef __attribute__((ext_vector_type(4))) float  floatx4;  // MFMA C/D frag
typedef __attribute__((ext_vector_type(8))) unsigned short ushort8v;
typedef __attribute__((ext_vector_type(4))) unsigned short ushort4v;

// Half-up rounding (2 VALU): differs from RNE only on exact 0x8000 ties (p~2^-16).
__device__ __forceinline__ unsigned short f2bf(float f) {
    return (unsigned short)((__float_as_uint(f) + 0x8000u) >> 16);
}

__device__ __forceinline__ void gload_lds16(const void* g, void* l) {
    // async global->LDS, 16B/lane; LDS dest = wave-uniform base + lane*16
    __builtin_amdgcn_global_load_lds(
        (const __attribute__((address_space(1))) unsigned int*)g,
        (__attribute__((address_space(3))) unsigned int*)l, 16, 0, 0);
}

// ---------------------------------------------------------------------------
// fp32 -> bf16: keys, values (z selects). 8 elems/thread.
// ---------------------------------------------------------------------------
__global__ __launch_bounds__(256)
void convert_kv(const float* __restrict__ K, const float* __restrict__ V,
                unsigned short* __restrict__ Kbf, unsigned short* __restrict__ Vbf)
{
    const float* src = blockIdx.z ? V : K;
    unsigned short* dst = blockIdx.z ? Vbf : Kbf;
    size_t i = ((size_t)blockIdx.x * 256 + threadIdx.x) * 8;
    float4 u0 = *(const float4*)&src[i];
    float4 u1 = *(const float4*)&src[i + 4];
    ushort8v o8;
    o8[0] = f2bf(u0.x); o8[1] = f2bf(u0.y); o8[2] = f2bf(u0.z); o8[3] = f2bf(u0.w);
    o8[4] = f2bf(u1.x); o8[5] = f2bf(u1.y); o8[6] = f2bf(u1.z); o8[7] = f2bf(u1.w);
    *(ushort8v*)&dst[i] = o8;
}

// ---------------------------------------------------------------------------
// Transpose+convert: W [K][N] fp32 -> WT [N][K] bf16. 32x32 LDS tiles.
// ---------------------------------------------------------------------------
__global__ __launch_bounds__(256)
void transpose_w(const float* __restrict__ W0, const float* __restrict__ W1,
                 const float* __restrict__ W2, const float* __restrict__ W3,
                 unsigned short* __restrict__ T0, unsigned short* __restrict__ T1,
                 unsigned short* __restrict__ T2, unsigned short* __restrict__ T3)
{
    int z = blockIdx.z;
    const float* W = (z == 0) ? W0 : (z == 1) ? W1 : (z == 2) ? W2 : W3;
    unsigned short* T = (z == 0) ? T0 : (z == 1) ? T1 : (z == 2) ? T2 : T3;
    __shared__ float t[32][33];
    const int tid = threadIdx.x;
    const int k0 = blockIdx.y * 32, n0 = blockIdx.x * 32;
    {
        int r = tid >> 3, c4 = (tid & 7) * 4;
        float4 u = *(const float4*)&W[(size_t)(k0 + r) * DM + n0 + c4];
        t[r][c4 + 0] = u.x; t[r][c4 + 1] = u.y; t[r][c4 + 2] = u.z; t[r][c4 + 3] = u.w;
    }
    __syncthreads();
    {
        int n = tid >> 3, k4 = (tid & 7) * 4;
        ushort4v o;
        o[0] = f2bf(t[k4 + 0][n]); o[1] = f2bf(t[k4 + 1][n]);
        o[2] = f2bf(t[k4 + 2][n]); o[3] = f2bf(t[k4 + 3][n]);
        *(ushort4v*)&T[(size_t)(n0 + n) * DM + k0 + k4] = o;
    }
}

// ---------------------------------------------------------------------------
// Fused Q/K/V projection, grid (8,32,3), tile 128x128, BK=64 (16 iters —
// r9 counters: 1800 cyc/block-iter vs ~100 of work -> barrier-drain bound;
// halve the barrier count, double work per drain).
// z=0: Qh = queries@WqT^T (fp32 convert-in-staging A)    -> d_out lo   [B,H,S,E]
// z=1: Kh = Kbf   @WkT^T  (ALL-ASYNC)                    -> d_out hi   [B,H,S,E]
// z=2: Vt = WvT @ Vbf^T   (ALL-ASYNC, transposed form)   -> ws         [B,H,E,S]
// XOR chunk swizzle (attn-proven, ~1e6 conflicts) on all LDS tiles.
// XCD swizzle pins the big operand's tile (r8: FETCH 133->49MB).
// ---------------------------------------------------------------------------
struct ProjArgs {
    const float* queries;
    const unsigned short* Kbf;
    const unsigned short* Vbf;
    const unsigned short* wt[3];    // WqT, WkT, WvT
    const float* bias[3];
    unsigned short* C[3];           // Qh, Kh, Vt
    float qscale;
};

__global__ __launch_bounds__(256)
void proj_qkv(ProjArgs pa)
{
    const int z = blockIdx.z;
    const bool vt = (z == 2);
    const int linear = (int)(blockIdx.x + gridDim.x * blockIdx.y);  // 0..255
    int rb, cb;
    if (!vt) { rb = linear & 31; cb = linear >> 5; }   // pin activation row-tile
    else     { cb = linear & 31; rb = linear >> 5; }   // pin values tile
    const int row0 = rb * 128, col0 = cb * 128;

    // A rows: z=0 queries(fp32)@row0, z=1 Kbf@row0, z=2 WvT@row0
    // B rows: z=0 WqT@col0, z=1 WkT@col0, z=2 Vbf@col0
    const unsigned short* aSrc = (z == 1) ? pa.Kbf : pa.wt[2];
    const unsigned short* bSrc = (z == 0) ? pa.wt[0] : (z == 1) ? pa.wt[1] : pa.Vbf;

    __shared__ unsigned short As[128 * 64];   // XOR-swizzled 8-chunk rows
    __shared__ unsigned short Bs[128 * 64];

    const int tid = threadIdx.x;
    const int lane = tid & 63, w = tid >> 6;
    const int lane15 = lane & 15, quad = lane >> 4;

    floatx4 acc[2][8] = {};

    for (int kt = 0; kt < DM; kt += 64) {
        __syncthreads();
        if (z == 0) {
            // fp32 convert staging: 1024 chunks of 16B, 4/thread
#pragma unroll
            for (int rr = 0; rr < 4; ++rr) {
                int p = rr * 256 + tid;
                int row = p >> 3, gch = (p & 7) ^ (row & 7);
                const float* s = &pa.queries[(size_t)(row0 + row) * DM + kt + gch * 8];
                float4 u0 = *(const float4*)s;
                float4 u1 = *(const float4*)(s + 4);
                ushort8v o8;
                o8[0] = f2bf(u0.x); o8[1] = f2bf(u0.y); o8[2] = f2bf(u0.z); o8[3] = f2bf(u0.w);
                o8[4] = f2bf(u1.x); o8[5] = f2bf(u1.y); o8[6] = f2bf(u1.z); o8[7] = f2bf(u1.w);
                *(ushort8v*)&As[(size_t)p * 8] = o8;
            }
        } else {
#pragma unroll
            for (int rr = 0; rr < 4; ++rr) {
                int p = rr * 256 + w * 64 + lane;
                int row = p >> 3, gch = (p & 7) ^ (row & 7);
                gload_lds16(&aSrc[(size_t)(row0 + row) * DM + kt + gch * 8],
                            (char*)As + (size_t)(rr * 256 + w * 64) * 16);
            }
        }
#pragma unroll
        for (int rr = 0; rr < 4; ++rr) {
            int p = rr * 256 + w * 64 + lane;
            int row = p >> 3, gch = (p & 7) ^ (row & 7);
            gload_lds16(&bSrc[(size_t)(col0 + row) * DM + kt + gch * 8],
                        (char*)Bs + (size_t)(rr * 256 + w * 64) * 16);
        }
        __syncthreads();

#pragma unroll
        for (int ks = 0; ks < 2; ++ks) {
            short8 af[2], bf[8];
#pragma unroll
            for (int i = 0; i < 2; ++i) {
                int r = w * 32 + i * 16 + lane15;
                af[i] = *(const short8*)&As[r * 64 + (((ks * 4 + quad) ^ (r & 7)) << 3)];
            }
#pragma unroll
            for (int j = 0; j < 8; ++j) {
                int r = j * 16 + lane15;
                bf[j] = *(const short8*)&Bs[r * 64 + (((ks * 4 + quad) ^ (r & 7)) << 3)];
            }
#pragma unroll
            for (int i = 0; i < 2; ++i)
#pragma unroll
                for (int j = 0; j < 8; ++j)
                    acc[i][j] = __builtin_amdgcn_mfma_f32_16x16x32_bf16(af[i], bf[j], acc[i][j], 0, 0, 0);
        }
    }

    const float* bias = pa.bias[z];
    const float os = (z == 0) ? pa.qscale : 1.f;
    unsigned short* C = pa.C[z];
#pragma unroll
    for (int i = 0; i < 2; ++i) {
#pragma unroll
        for (int j = 0; j < 8; ++j) {
#pragma unroll
            for (int r = 0; r < 4; ++r) {
                int row = row0 + w * 32 + i * 16 + quad * 4 + r;
                int col = col0 + j * 16 + lane15;
                if (!vt) {
                    float v = (acc[i][j][r] + bias[col]) * os;
                    int b = row >> 11, l = row & (SEQ - 1);
                    int h = col >> 6,  e = col & (EH - 1);
                    C[((size_t)(b * NH + h) * SEQ + l) * EH + e] = f2bf(v);
                } else {
                    float v = acc[i][j][r] + bias[row];       // bias by e-row
                    int h = row >> 6,  e = row & (EH - 1);
                    int b = col >> 11, l = col & (SEQ - 1);
                    C[((size_t)(b * NH + h) * EH + e) * SEQ + l] = f2bf(v);
                }
            }
        }
    }
}

// ---------------------------------------------------------------------------
// Output projection: out[4096][1024] fp32 = ctx(bf16) @ WoT^T + bo.
// Tile 128x64 (NT=4), BK=64, grid (16,32), all-async, XOR swizzle,
// XCD swizzle pins the ctx row-tile.
// ---------------------------------------------------------------------------
__global__ __launch_bounds__(256)
void gemm_out(const unsigned short* __restrict__ ctx,
              const unsigned short* __restrict__ WoT,
              const float* __restrict__ bo,
              float* __restrict__ out)
{
    const int linear = (int)(blockIdx.x + gridDim.x * blockIdx.y);  // 0..511
    const int rb = linear & 31, cb = linear >> 5;                   // cb 0..15
    const int row0 = rb * 128, col0 = cb * 64;

    __shared__ unsigned short As[128 * 64];
    __shared__ unsigned short Bs[64 * 64];

    const int tid = threadIdx.x;
    const int lane = tid & 63, w = tid >> 6;
    const int lane15 = lane & 15, quad = lane >> 4;

    floatx4 acc[2][4] = {};

    for (int kt = 0; kt < DM; kt += 64) {
        __syncthreads();
#pragma unroll
        for (int rr = 0; rr < 4; ++rr) {          // A: 1024 chunks
            int p = rr * 256 + w * 64 + lane;
            int row = p >> 3, gch = (p & 7) ^ (row & 7);
            gload_lds16(&ctx[(size_t)(row0 + row) * DM + kt + gch * 8],
                        (char*)As + (size_t)(rr * 256 + w * 64) * 16);
        }
#pragma unroll
        for (int rr = 0; rr < 2; ++rr) {          // B: 512 chunks
            int p = rr * 256 + w * 64 + lane;
            int row = p >> 3, gch = (p & 7) ^ (row & 7);
            gload_lds16(&WoT[(size_t)(col0 + row) * DM + kt + gch * 8],
                        (char*)Bs + (size_t)(rr * 256 + w * 64) * 16);
        }
        __syncthreads();

#pragma unroll
        for (int ks = 0; ks < 2; ++ks) {
            short8 af[2], bf[4];
#pragma unroll
            for (int i = 0; i < 2; ++i) {
                int r = w * 32 + i * 16 + lane15;
                af[i] = *(const short8*)&As[r * 64 + (((ks * 4 + quad) ^ (r & 7)) << 3)];
            }
#pragma unroll
            for (int j = 0; j < 4; ++j) {
                int r = j * 16 + lane15;
                bf[j] = *(const short8*)&Bs[r * 64 + (((ks * 4 + quad) ^ (r & 7)) << 3)];
            }
#pragma unroll
            for (int i = 0; i < 2; ++i)
#pragma unroll
                for (int j = 0; j < 4; ++j)
                    acc[i][j] = __builtin_amdgcn_mfma_f32_16x16x32_bf16(af[i], bf[j], acc[i][j], 0, 0, 0);
        }
    }

#pragma unroll
    for (int i = 0; i < 2; ++i)
#pragma unroll
        for (int j = 0; j < 4; ++j)
#pragma unroll
            for (int r = 0; r < 4; ++r) {
                int row = row0 + w * 32 + i * 16 + quad * 4 + r;
                int col = col0 + j * 16 + lane15;
                out[(size_t)row * DM + col] = acc[i][j][r] + bo[col];
            }
}

// ---------------------------------------------------------------------------
// MFMA flash attention (r9 core, unchanged): (b,h)-pinned XCD swizzle;
// S^T = K @ Q^T; max-free softmax; l = P @ ones MFMA; exp2 builtin;
// K/V async-staged XOR-swizzled double-buffered, 1 barrier/iter.
// Q pre-scaled by 0.125*log2(e). Qh,Kh:[B,H,S,E]; Vt:[B,H,E,S]; ctx:[4096][1024].
// ---------------------------------------------------------------------------
__device__ __forceinline__ void stage_kv(const unsigned short* __restrict__ Kp,
                                         const unsigned short* __restrict__ Vp,
                                         int st, unsigned short* ksb, unsigned short* vsb,
                                         int w, int lane)
{
#pragma unroll
    for (int rr = 0; rr < 2; ++rr) {
        int p = rr * 256 + w * 64 + lane;      // LDS chunk position
        int row = p >> 3;
        int gch = (p & 7) ^ (row & 7);         // swizzled source chunk
        gload_lds16(&Kp[(size_t)(st + row) * EH + gch * 8],
                    ksb + (size_t)(rr * 256 + w * 64) * 8);
        gload_lds16(&Vp[(size_t)row * SEQ + st + gch * 8],
                    vsb + (size_t)(rr * 256 + w * 64) * 8);
    }
}

__global__ __launch_bounds__(256)
void attn_mfma(const unsigned short* __restrict__ Qh,
               const unsigned short* __restrict__ Kh,
               const unsigned short* __restrict__ Vt,
               unsigned short* __restrict__ ctx)
{
    __shared__ unsigned short Ks[2][64 * 64];   // swizzled [s][e]
    __shared__ unsigned short Vs[2][64 * 64];   // swizzled [e][s]
    __shared__ unsigned short Ps[128][72];      // [q_local][s], padded pitch

    const int tid = threadIdx.x;
    const int lane = tid & 63, w = tid >> 6;
    const int lane15 = lane & 15, quad = lane >> 4;

    // (b,h)-pinned swizzle: linear%8 == bh%8 -> K/V L2 reuse within an XCD
    const int linear = (int)(blockIdx.x + 16 * (blockIdx.y + 16 * blockIdx.z));
    const int bhid = linear & 31;      // 0..31
    const int qt = linear >> 5;        // 0..15
    const int h = bhid & 15, b = bhid >> 4;

    const size_t bh = (size_t)(b * NH + h);
    const unsigned short* Kp = Kh + bh * SEQ * EH;
    const unsigned short* Vp = Vt + bh * EH * SEQ;

    short8 qf[2][2];
    {
        const unsigned short* Qp =
            Qh + (bh * SEQ + (size_t)qt * 128 + w * 32 + lane15) * EH;
#pragma unroll
        for (int ks = 0; ks < 2; ++ks) {
            qf[0][ks] = *(const short8*)(Qp + ks * 32 + quad * 8);
            qf[1][ks] = *(const short8*)(Qp + 16 * EH + ks * 32 + quad * 8);
        }
    }
    short8 ones;
#pragma unroll
    for (int i = 0; i < 8; ++i) ones[i] = (short)0x3F80;   // bf16 1.0

    floatx4 o[2][4] = {};
    floatx4 lacc[2] = {};

    stage_kv(Kp, Vp, 0, Ks[0], Vs[0], w, lane);
    __syncthreads();
    int cur = 0;

    for (int st = 0; st < SEQ; st += 64) {
        int nxt = cur ^ 1;
        if (st + 64 < SEQ)
            stage_kv(Kp, Vp, st + 64, Ks[nxt], Vs[nxt], w, lane);
        const unsigned short* ksb = Ks[cur];
        const unsigned short* vsb = Vs[cur];

        floatx4 sacc[4][2] = {};
#pragma unroll
        for (int ts = 0; ts < 4; ++ts) {
#pragma unroll
            for (int ks = 0; ks < 2; ++ks) {
                short8 kf = *(const short8*)&ksb[((ts * 16 + lane15) << 6) +
                                                 ((((ks << 2) + quad) ^ (lane15 & 7)) << 3)];
                sacc[ts][0] = __builtin_amdgcn_mfma_f32_16x16x32_bf16(kf, qf[0][ks], sacc[ts][0], 0, 0, 0);
                sacc[ts][1] = __builtin_amdgcn_mfma_f32_16x16x32_bf16(kf, qf[1][ks], sacc[ts][1], 0, 0, 0);
            }
        }

        // P = exp2(S'); pack 4 consecutive-s bf16 -> one ds_write_b64 per tile
#pragma unroll
        for (int ts = 0; ts < 4; ++ts)
#pragma unroll
            for (int nq = 0; nq < 2; ++nq) {
                unsigned int u0 = __float_as_uint(__builtin_amdgcn_exp2f(sacc[ts][nq][0])) + 0x8000u;
                unsigned int u1 = __float_as_uint(__builtin_amdgcn_exp2f(sacc[ts][nq][1])) + 0x8000u;
                unsigned int u2 = __float_as_uint(__builtin_amdgcn_exp2f(sacc[ts][nq][2])) + 0x8000u;
                unsigned int u3 = __float_as_uint(__builtin_amdgcn_exp2f(sacc[ts][nq][3])) + 0x8000u;
                uint2 pk;
                pk.x = (u0 >> 16) | (u1 & 0xFFFF0000u);
                pk.y = (u2 >> 16) | (u3 & 0xFFFF0000u);
                *(uint2*)&Ps[w * 32 + nq * 16 + lane15][ts * 16 + quad * 4] = pk;
            }

        // O += P @ V ; l += P @ 1   (Ps rows wave-local: no barrier needed)
#pragma unroll
        for (int ks = 0; ks < 2; ++ks) {
            short8 pf[2];
#pragma unroll
            for (int mt = 0; mt < 2; ++mt) {
                pf[mt] = *(const short8*)&Ps[w * 32 + mt * 16 + lane15][ks * 32 + quad * 8];
                lacc[mt] = __builtin_amdgcn_mfma_f32_16x16x32_bf16(pf[mt], ones, lacc[mt], 0, 0, 0);
            }
#pragma unroll
            for (int t2 = 0; t2 < 4; ++t2) {
                short8 vf = *(const short8*)&vsb[((t2 * 16 + lane15) << 6) +
                                                 ((((ks << 2) + quad) ^ (lane15 & 7)) << 3)];
                o[0][t2] = __builtin_amdgcn_mfma_f32_16x16x32_bf16(pf[0], vf, o[0][t2], 0, 0, 0);
                o[1][t2] = __builtin_amdgcn_mfma_f32_16x16x32_bf16(pf[1], vf, o[1][t2], 0, 0, 0);
            }
        }
        __syncthreads();
        cur = nxt;
    }

#pragma unroll
    for (int mt = 0; mt < 2; ++mt) {
        float inv[4];
#pragma unroll
        for (int r = 0; r < 4; ++r) inv[r] = 1.0f / lacc[mt][r];
#pragma unroll
        for (int t2 = 0; t2 < 4; ++t2)
#pragma unroll
            for (int r = 0; r < 4; ++r) {
                int q = qt * 128 + w * 32 + mt * 16 + quad * 4 + r;
                int col = h * EH + t2 * 16 + lane15;
                ctx[((size_t)(b * SEQ + q)) * DM + col] = f2bf(o[mt][t2][r] * inv[r]);
            }
    }
}

extern "C" void kernel_launch(void* const* d_in, const int* in_sizes, int n_in,
                              void* d_out, int out_size, void* d_ws, size_t ws_size,
                              hipStream_t stream)
{
    const float* queries = (const float*)d_in[0];
    const float* keys    = (const float*)d_in[1];
    const float* values  = (const float*)d_in[2];
    const float* Wq = (const float*)d_in[3];
    const float* bq = (const float*)d_in[4];
    const float* Wk = (const float*)d_in[5];
    const float* bk = (const float*)d_in[6];
    const float* Wv = (const float*)d_in[7];
    const float* bv = (const float*)d_in[8];
    const float* Wo = (const float*)d_in[9];
    const float* bo = (const float*)d_in[10];
    float* out = (float*)d_out;

    // ws 32 MB (ushort elems): Kbf | Vbf | Vt | weights(WqT,WkT,WvT,WoT)
    // d_out 16 MB used as scratch: Qh (lo 8MB) | Kh (hi 8MB) — fully
    // overwritten by gemm_out at the end. ctx reuses the Kbf region (dead
    // after proj).
    unsigned short* ws = (unsigned short*)d_ws;
    const size_t MAT = (size_t)MROWS * DM;   // 4M elems (8 MB bf16)
    const size_t WSZ = (size_t)DM * DM;      // 1M elems (2 MB bf16)
    unsigned short* Kbf = ws;                // [0,4M)
    unsigned short* Vbf = ws + MAT;          // [4M,8M)
    unsigned short* Vtp = ws + 2 * MAT;      // [8M,12M)
    unsigned short* WqT = ws + 3 * MAT;      // [12M,16M): 4 weights
    unsigned short* WkT = WqT + WSZ;
    unsigned short* WvT = WqT + 2 * WSZ;
    unsigned short* WoT = WqT + 3 * WSZ;
    unsigned short* ctx = ws;                // alias Kbf (dead after proj)
    unsigned short* Qhp = (unsigned short*)d_out;        // d_out lo 8MB
    unsigned short* Khp = (unsigned short*)d_out + MAT;  // d_out hi 8MB

    // 1/sqrt(EH) * log2(e): exp2(S') == exp(S/8)
    const float qscale = 0.125f * 1.44269504088896f;

    // 1. all four weight transposes
    transpose_w<<<dim3(DM / 32, DM / 32, 4), 256, 0, stream>>>(
        Wq, Wk, Wv, Wo, WqT, WkT, WvT, WoT);

    // 2. keys/values -> bf16
    convert_kv<<<dim3(MAT / 2048, 1, 2), 256, 0, stream>>>(keys, values, Kbf, Vbf);

    // 3. fused Q/K/V projections (K/V all-async; Q converts in staging)
    ProjArgs pa;
    pa.queries = queries; pa.Kbf = Kbf; pa.Vbf = Vbf;
    pa.wt[0] = WqT; pa.wt[1] = WkT; pa.wt[2] = WvT;
    pa.bias[0] = bq; pa.bias[1] = bk; pa.bias[2] = bv;
    pa.C[0] = Qhp; pa.C[1] = Khp; pa.C[2] = Vtp;
    pa.qscale = qscale;
    proj_qkv<<<dim3(8, 32, 3), 256, 0, stream>>>(pa);

    // 4. attention -> ctx (Kbf region, dead)
    attn_mfma<<<dim3(SEQ / 128, NH, BATCH), 256, 0, stream>>>(Qhp, Khp, Vtp, ctx);

    // 5. output projection -> d_out (overwrites Qh/Kh scratch, dead)
    gemm_out<<<dim3(16, 32), 256, 0, stream>>>(ctx, WoT, bo, out);
}